// Round 12
// baseline (221.571 us; speedup 1.0000x reference)
//
#include <hip/hip_runtime.h>
#include <stdint.h>

#define N_NODES_C 20000
#define N_EDGES_C 320000
#define NUM_RELS_C 16
#define FEAT_C 256
#define CAP_LOG2 6             // 64 slots per dst in direct-bucket fast path
#define GEMM_HALF_BLOCKS 2512  // 157 m-tiles * 16 (8 rels * 2 n-halves)
#define WS_FAST_BYTES 186497152ULL

typedef __bf16 bf16_t;
typedef __bf16 bf16x8 __attribute__((ext_vector_type(8)));
typedef __bf16 bf16x4 __attribute__((ext_vector_type(4)));
typedef float f32x4 __attribute__((ext_vector_type(4)));

__device__ __forceinline__ void async_load16(const void* g, void* l) {
  __builtin_amdgcn_global_load_lds(
      (__attribute__((address_space(1))) void*)const_cast<void*>(g),
      (__attribute__((address_space(3))) void*)l, 16, 0, 0);
}

// ---- aggregate body: per-dst gather-reduce over 64-slot bins.
// PART: -1 = all rels, 0 = rel<8, 1 = rel>=8 (bit 19 of packed meta; wave-uniform
// predicate, no divergence). ACCUM: 0 = store, 1 = accumulate into out.
// Lane l reads permuted positions 4l..4l+3 (byte off 8l) of the 512B row;
// de-permute on write: position 4l+j holds col (4l&192) + j*16 + (l&15).
template <int PART, int ACCUM>
__device__ __forceinline__ void agg_body(int blk, int tid,
                                         const bf16_t* __restrict__ Tb,
                                         const int* __restrict__ cnt,
                                         const int2* __restrict__ bkt,
                                         float* __restrict__ out) {
  int d = blk * 4 + (tid >> 6);
  int lane = tid & 63;
  int p0 = d << CAP_LOG2;
  int p1 = p0 + cnt[d];
  int boff = lane << 3;
  float a0 = 0.f, a1 = 0.f, a2 = 0.f, a3 = 0.f;
  int p = p0;
  for (; p + 8 <= p1; p += 8) {
    int2 m[8];
#pragma unroll
    for (int q = 0; q < 8; ++q) m[q] = bkt[p + q];
    bf16x4 v[8];
#pragma unroll
    for (int q = 0; q < 8; ++q)
      if (PART < 0 || ((m[q].x >> 19) & 1) == PART)
        v[q] = *(const bf16x4*)((const char*)(Tb + (((size_t)(m[q].x >> 16) * N_NODES_C + (m[q].x & 0xFFFF)) << 8)) + boff);
#pragma unroll
    for (int q = 0; q < 8; ++q)
      if (PART < 0 || ((m[q].x >> 19) & 1) == PART) {
        float nq = __int_as_float(m[q].y);
        a0 += (float)v[q][0] * nq;
        a1 += (float)v[q][1] * nq;
        a2 += (float)v[q][2] * nq;
        a3 += (float)v[q][3] * nq;
      }
  }
  for (; p < p1; ++p) {
    int2 mm = bkt[p];
    if (PART < 0 || ((mm.x >> 19) & 1) == PART) {
      bf16x4 v0 = *(const bf16x4*)((const char*)(Tb + (((size_t)(mm.x >> 16) * N_NODES_C + (mm.x & 0xFFFF)) << 8)) + boff);
      float n0 = __int_as_float(mm.y);
      a0 += (float)v0[0] * n0;
      a1 += (float)v0[1] * n0;
      a2 += (float)v0[2] * n0;
      a3 += (float)v0[3] * n0;
    }
  }
  float* o = out + (size_t)d * FEAT_C + ((lane << 2) & 192) + (lane & 15);
  if (ACCUM) {
    o[0] += a0; o[16] += a1; o[32] += a2; o[48] += a3;
  } else {
    o[0] = a0; o[16] = a1; o[32] = a2; o[48] = a3;
  }
}

// ================= FAST PATH (5 dispatches) =================
// prep_fast: [0,5000) h->bf16 | [5000,5256) W transpose via LDS tile |
// [5256,6506) direct-bucket edges (cnt zeroed by prior memset — R5/R6-proven order).
__global__ void prep_fast_kernel(const float* __restrict__ h, bf16_t* __restrict__ hB,
                                 const float* __restrict__ W, bf16_t* __restrict__ Wt,
                                 const int* __restrict__ dst, const int* __restrict__ src,
                                 const int* __restrict__ rel, const float* __restrict__ norm,
                                 int* __restrict__ cnt, int2* __restrict__ bkt) {
  int b = blockIdx.x;
  int t = threadIdx.x;
  if (b < 5000) {
    int i = (b * 256 + t) * 4;
    float4 v = *(const float4*)(h + i);
    bf16x4 o = { (bf16_t)v.x, (bf16_t)v.y, (bf16_t)v.z, (bf16_t)v.w };
    *(bf16x4*)(hB + i) = o;
  } else if (b < 5256) {
    // 64(i) x 64(o) tile transpose: W[r][i][o] f32 -> Wt[r][o][i] bf16
    __shared__ bf16_t lds[64][66];   // odd-dword row stride -> conflict-free
    int b2 = b - 5000;
    int r  = b2 >> 4;
    int i0 = ((b2 >> 2) & 3) << 6;
    int o0 = (b2 & 3) << 6;
    int tx = t & 15;
    int ty = t >> 4;
#pragma unroll
    for (int pass = 0; pass < 4; ++pass) {
      int il = ty + pass * 16;
      float4 v = *(const float4*)(W + (r << 16) + ((i0 + il) << 8) + o0 + tx * 4);
      lds[tx * 4 + 0][il] = (bf16_t)v.x;
      lds[tx * 4 + 1][il] = (bf16_t)v.y;
      lds[tx * 4 + 2][il] = (bf16_t)v.z;
      lds[tx * 4 + 3][il] = (bf16_t)v.w;
    }
    __syncthreads();
#pragma unroll
    for (int pass = 0; pass < 4; ++pass) {
      int ol = ty + pass * 16;
      bf16x4 pk = { lds[ol][tx * 4 + 0], lds[ol][tx * 4 + 1],
                    lds[ol][tx * 4 + 2], lds[ol][tx * 4 + 3] };
      *(bf16x4*)(Wt + (r << 16) + ((o0 + ol) << 8) + i0 + tx * 4) = pk;
    }
  } else {
    int e = (b - 5256) * 256 + t;
    if (e < N_EDGES_C) {
      int d = dst[e];
      int pos = (d << CAP_LOG2) + atomicAdd(&cnt[d], 1);
      int2 pk;
      pk.x = src[e] | (rel[e] << 16);
      pk.y = __float_as_int(norm[e]);
      bkt[pos] = pk;
    }
  }
}

// ---- half-gemm (+ optional aggregate-part-A tail): R2 tile/frag math +
// counted-vmcnt pipeline (frozen core, structure-bound at ~62 µs full / ~31 half).
// Blocks [0, GEMM_HALF_BLOCKS): gemm r in [RBASE, RBASE+8), both n-halves.
// If TAIL: blocks [GEMM_HALF_BLOCKS, +5000) run aggregate PART=0 (rel<8) — their
// gathers touch only Tb[r<8] (written by the previous dispatch); gemm here writes
// Tb[r>=8] — disjoint, no race. MFMA-bound gemm and memory-bound gather co-run.
template <int RBASE, bool TAIL>
__global__ __launch_bounds__(256) void gemm_agg_kernel(
    const bf16_t* __restrict__ hB, const bf16_t* __restrict__ Wt,
    bf16_t* __restrict__ Tb, const int* __restrict__ cnt,
    const int2* __restrict__ bkt, float* __restrict__ out) {
  int bx = blockIdx.x;
  int tid = threadIdx.x;

  if (TAIL && bx >= GEMM_HALF_BLOCKS) {
    agg_body<0, 0>(bx - GEMM_HALF_BLOCKS, tid, Tb, cnt, bkt, out);
    return;
  }

  int sub = bx & 15;
  int m0 = (bx >> 4) << 7;
  int r  = RBASE + (sub >> 1);
  int n0 = (sub & 1) << 7;

  __shared__ bf16_t Asm[3 * 128 * 32];   // 24 KB (triple-buffered)
  __shared__ bf16_t Bsm[3 * 128 * 32];   // 24 KB

  int lrow = tid >> 2;
  int pch = tid & 3;
  int rA0 = lrow, rA1 = lrow + 64;
  int lc0 = pch ^ ((rA0 >> 1) & 3);
  int lc1 = pch ^ ((rA1 >> 1) & 3);
  int gr0 = m0 + rA0; if (gr0 > N_NODES_C - 1) gr0 = N_NODES_C - 1;
  int gr1 = m0 + rA1; if (gr1 > N_NODES_C - 1) gr1 = N_NODES_C - 1;
  const char* gA0 = (const char*)(hB + (size_t)gr0 * FEAT_C) + lc0 * 16;
  const char* gA1 = (const char*)(hB + (size_t)gr1 * FEAT_C) + lc1 * 16;
  const char* gB0 = (const char*)(Wt + ((size_t)r * 256 + n0 + rA0) * FEAT_C) + lc0 * 16;
  const char* gB1 = (const char*)(Wt + ((size_t)r * 256 + n0 + rA1) * FEAT_C) + lc1 * 16;

  int wave = tid >> 6;
  int lane = tid & 63;
  int lq = lane >> 4;
  int lr = lane & 15;
  int wm = (wave >> 1) * 64;
  int wn = (wave & 1) * 64;
  int pc8 = (lq ^ ((lr >> 1) & 3)) * 8;

  f32x4 acc[4][4] = {};

#define STAGE(buf, t)                                             \
  do {                                                            \
    int kb_ = (t) * 64;                                           \
    char* aB_ = (char*)Asm + (buf) * 8192 + wave * 1024;          \
    char* bB_ = (char*)Bsm + (buf) * 8192 + wave * 1024;          \
    async_load16(gA0 + kb_, aB_);                                 \
    async_load16(gA1 + kb_, aB_ + 4096);                          \
    async_load16(gB0 + kb_, bB_);                                 \
    async_load16(gB1 + kb_, bB_ + 4096);                          \
  } while (0)

  STAGE(0, 0);
  STAGE(1, 1);

#pragma unroll
  for (int kk = 0; kk < 8; ++kk) {
    if (kk < 7) asm volatile("s_waitcnt vmcnt(4)" ::: "memory");
    else        asm volatile("s_waitcnt vmcnt(0)" ::: "memory");
    __builtin_amdgcn_s_barrier();
    __builtin_amdgcn_sched_barrier(0);
    const bf16_t* Ac = Asm + (kk % 3) * 4096;
    const bf16_t* Bc = Bsm + (kk % 3) * 4096;
    bf16x8 af[4], bfr[4];
#pragma unroll
    for (int mt = 0; mt < 4; ++mt) {
      int row = wm + mt * 16 + lr;
      af[mt] = *(const bf16x8*)&Ac[row * 32 + pc8];
    }
#pragma unroll
    for (int nt2 = 0; nt2 < 4; ++nt2) {
      int row = wn + nt2 * 16 + lr;
      bfr[nt2] = *(const bf16x8*)&Bc[row * 32 + pc8];
    }
    if (kk < 6) STAGE((kk + 2) % 3, kk + 2);
#pragma unroll
    for (int mt = 0; mt < 4; ++mt)
#pragma unroll
      for (int nt2 = 0; nt2 < 4; ++nt2)
        acc[mt][nt2] = __builtin_amdgcn_mfma_f32_16x16x32_bf16(af[mt], bfr[nt2], acc[mt][nt2], 0, 0, 0);
  }
#undef STAGE

  // Epilogue: 16B/lane stores via parity-pair shfl_xor merge (layout unchanged:
  // permuted position p = 4*lr' + nt holds col nt*16 + lr' within the n0+wn group).
#pragma unroll
  for (int mt = 0; mt < 4; ++mt) {
#pragma unroll
    for (int a = 0; a < 2; ++a) {
      int rg0 = a * 2, rg1 = rg0 + 1;
      union { bf16x4 v; long long u; } q0, q1;
      q0.v = (bf16x4){ (bf16_t)acc[mt][0][rg0], (bf16_t)acc[mt][1][rg0],
                       (bf16_t)acc[mt][2][rg0], (bf16_t)acc[mt][3][rg0] };
      q1.v = (bf16x4){ (bf16_t)acc[mt][0][rg1], (bf16_t)acc[mt][1][rg1],
                       (bf16_t)acc[mt][2][rg1], (bf16_t)acc[mt][3][rg1] };
      int odd = lr & 1;
      long long send = odd ? q0.u : q1.u;
      long long got = __shfl_xor(send, 1);
      union { bf16x8 v; long long u[2]; } w;
      w.u[0] = odd ? got : q0.u;
      w.u[1] = odd ? q1.u : got;
      int rg = rg0 + odd;
      int row = m0 + wm + mt * 16 + lq * 4 + rg;
      if (row < N_NODES_C) {
        int pos = n0 + wn + ((lr >> 1) << 3);
        *(bf16x8*)(Tb + (((size_t)r * N_NODES_C + row) << 8) + pos) = w.v;
      }
    }
  }
}

// ---- aggregate part B (rel>=8), accumulating into out ----
__global__ __launch_bounds__(256) void agg_partB_kernel(
    const bf16_t* __restrict__ Tb, const int* __restrict__ cnt,
    const int2* __restrict__ bkt, float* __restrict__ out) {
  agg_body<1, 1>(blockIdx.x, threadIdx.x, Tb, cnt, bkt, out);
}

// ================= SLOW PATH (known-good CSR chain) =================
__global__ void prep_kernel(const float* __restrict__ h, bf16_t* __restrict__ hB,
                            const float* __restrict__ W, bf16_t* __restrict__ Wt,
                            const int* __restrict__ dst, int* __restrict__ dcur) {
  int b = blockIdx.x;
  int t = threadIdx.x;
  if (b < 5000) {
    int i = (b * 256 + t) * 4;
    float4 v = *(const float4*)(h + i);
    bf16x4 o = { (bf16_t)v.x, (bf16_t)v.y, (bf16_t)v.z, (bf16_t)v.w };
    *(bf16x4*)(hB + i) = o;
  } else if (b < 9096) {
    int g = (b - 5000) * 256 + t;
    int i = g & 255;
    int o = (g >> 8) & 255;
    int r = g >> 16;
    Wt[(r << 16) + (o << 8) + i] = (bf16_t)W[(r << 16) + (i << 8) + o];
  } else {
    int e = (b - 9096) * 256 + t;
    if (e < N_EDGES_C) atomicAdd(&dcur[dst[e]], 1);
  }
}

__global__ void scan_dst_kernel(int* __restrict__ dcur, int* __restrict__ dstart) {
  __shared__ unsigned short cnt[20224];
  __shared__ int wsum[4];
  const int CH = 79;
  int t = threadIdx.x;
  int base = t * CH;
  int sum = 0;
  for (int i = 0; i < CH; ++i) {
    int idx = base + i;
    int c = (idx < N_NODES_C) ? dcur[idx] : 0;
    cnt[idx] = (unsigned short)c;
    sum += c;
  }
  int v = sum;
#pragma unroll
  for (int off = 1; off < 64; off <<= 1) {
    int u = __shfl_up(v, off);
    if ((t & 63) >= off) v += u;
  }
  if ((t & 63) == 63) wsum[t >> 6] = v;
  __syncthreads();
  int add = 0;
  for (int w = 0; w < (t >> 6); ++w) add += wsum[w];
  int run = v - sum + add;
  for (int i = 0; i < CH; ++i) {
    int idx = base + i;
    if (idx < N_NODES_C) {
      int c = cnt[idx];
      dstart[idx] = run;
      dcur[idx] = run;
      run += c;
    }
  }
  if (t == 0) dstart[N_NODES_C] = N_EDGES_C;
}

__global__ void bucket_dst_kernel(const int* __restrict__ dst, const int* __restrict__ src,
                                  const int* __restrict__ rel, const float* __restrict__ norm,
                                  int* __restrict__ dcur, int2* __restrict__ bkt) {
  int e = blockIdx.x * blockDim.x + threadIdx.x;
  if (e < N_EDGES_C) {
    int pos = atomicAdd(&dcur[dst[e]], 1);
    int2 pk;
    pk.x = src[e] | (rel[e] << 16);
    pk.y = __float_as_int(norm[e]);
    bkt[pos] = pk;
  }
}

// CSR full aggregate (slow path), proven R11 version.
__global__ __launch_bounds__(256) void aggregate_csr_kernel(
    const bf16_t* __restrict__ Tb, const int* __restrict__ dstart,
    const int2* __restrict__ bkt, float* __restrict__ out) {
  int tid = threadIdx.x;
  int d = blockIdx.x * 4 + (tid >> 6);
  int lane = tid & 63;
  int p0 = dstart[d];
  int p1 = dstart[d + 1];
  int boff = lane << 3;
  float a0 = 0.f, a1 = 0.f, a2 = 0.f, a3 = 0.f;
  int p = p0;
  for (; p + 8 <= p1; p += 8) {
    int2 m[8];
#pragma unroll
    for (int q = 0; q < 8; ++q) m[q] = bkt[p + q];
    bf16x4 v[8];
#pragma unroll
    for (int q = 0; q < 8; ++q)
      v[q] = *(const bf16x4*)((const char*)(Tb + (((size_t)(m[q].x >> 16) * N_NODES_C + (m[q].x & 0xFFFF)) << 8)) + boff);
#pragma unroll
    for (int q = 0; q < 8; ++q) {
      float nq = __int_as_float(m[q].y);
      a0 += (float)v[q][0] * nq;
      a1 += (float)v[q][1] * nq;
      a2 += (float)v[q][2] * nq;
      a3 += (float)v[q][3] * nq;
    }
  }
  for (; p < p1; ++p) {
    int2 m0 = bkt[p];
    bf16x4 v0 = *(const bf16x4*)((const char*)(Tb + (((size_t)(m0.x >> 16) * N_NODES_C + (m0.x & 0xFFFF)) << 8)) + boff);
    float n0 = __int_as_float(m0.y);
    a0 += (float)v0[0] * n0;
    a1 += (float)v0[1] * n0;
    a2 += (float)v0[2] * n0;
    a3 += (float)v0[3] * n0;
  }
  float* o = out + (size_t)d * FEAT_C + ((lane << 2) & 192) + (lane & 15);
  o[0]  = a0;
  o[16] = a1;
  o[32] = a2;
  o[48] = a3;
}

extern "C" void kernel_launch(void* const* d_in, const int* in_sizes, int n_in,
                              void* d_out, int out_size, void* d_ws, size_t ws_size,
                              hipStream_t stream) {
  const float* h    = (const float*)d_in[0];
  const float* W    = (const float*)d_in[1];
  const float* norm = (const float*)d_in[2];
  const int*   src  = (const int*)d_in[3];
  const int*   dst  = (const int*)d_in[4];
  const int*   rel  = (const int*)d_in[5];
  float* out = (float*)d_out;

  char* ws = (char*)d_ws;
  bf16_t* hB   = (bf16_t*)ws;                          // 10,240,000 B
  bf16_t* Wt   = (bf16_t*)(ws + 10240000);             //  2,097,152 B
  bf16_t* Tb   = (bf16_t*)(ws + 12337152);             // 163,840,000 B -> 176,177,152

  if (ws_size >= WS_FAST_BYTES) {
    // ---- fast path: memset + prep(+bucket) + [gemmA] + [gemmB || aggA] + [aggB] ----
    int* cnt  = (int*)(ws + 176177152);                // 80,000 B
    int2* bkt = (int2*)(ws + 176257152);               // 10,240,000 B -> 186,497,152
    hipMemsetAsync(cnt, 0, N_NODES_C * sizeof(int), stream);
    prep_fast_kernel<<<6506, 256, 0, stream>>>(h, hB, W, Wt, dst, src, rel, norm, cnt, bkt);
    gemm_agg_kernel<0, false><<<GEMM_HALF_BLOCKS, 256, 0, stream>>>(hB, Wt, Tb, cnt, bkt, out);
    gemm_agg_kernel<8, true><<<GEMM_HALF_BLOCKS + 5000, 256, 0, stream>>>(hB, Wt, Tb, cnt, bkt, out);
    agg_partB_kernel<<<5000, 256, 0, stream>>>(Tb, cnt, bkt, out);
  } else {
    // ---- slow path: known-good CSR chain ----
    int* dstart  = (int*)(ws + 176177152);             // 80,016 B
    int* dcur    = (int*)(ws + 176257168);             // 80,000 B
    int2* bkt    = (int2*)(ws + 176337168);            // 2,560,000 B -> ~178.9 MB
    hipMemsetAsync(dcur, 0, N_NODES_C * sizeof(int), stream);
    prep_kernel<<<10346, 256, 0, stream>>>(h, hB, W, Wt, dst, dcur);
    scan_dst_kernel<<<1, 256, 0, stream>>>(dcur, dstart);
    bucket_dst_kernel<<<1250, 256, 0, stream>>>(dst, src, rel, norm, dcur, bkt);
    gemm_agg_kernel<0, false><<<GEMM_HALF_BLOCKS, 256, 0, stream>>>(hB, Wt, Tb, dstart, bkt, out);
    gemm_agg_kernel<8, false><<<GEMM_HALF_BLOCKS, 256, 0, stream>>>(hB, Wt, Tb, dstart, bkt, out);
    aggregate_csr_kernel<<<5000, 256, 0, stream>>>(Tb, dstart, bkt, out);
  }
}

// Round 13
// 192.422 us; speedup vs baseline: 1.1515x; 1.1515x over previous
//
#include <hip/hip_runtime.h>
#include <stdint.h>

#define N_NODES_C 20000
#define N_EDGES_C 320000
#define NUM_RELS_C 16
#define FEAT_C 256
#define CAP_LOG2 6           // 64 slots per dst in direct-bucket fast path
#define GEMM_BLOCKS 5024     // 157 m-tiles * 32 (r*2 + n_half)
#define WS_FAST_BYTES 186497152ULL

typedef __bf16 bf16_t;
typedef __bf16 bf16x8 __attribute__((ext_vector_type(8)));
typedef __bf16 bf16x4 __attribute__((ext_vector_type(4)));
typedef float f32x4 __attribute__((ext_vector_type(4)));

__device__ __forceinline__ void async_load16(const void* g, void* l) {
  __builtin_amdgcn_global_load_lds(
      (__attribute__((address_space(1))) void*)const_cast<void*>(g),
      (__attribute__((address_space(3))) void*)l, 16, 0, 0);
}

// ================= FAST PATH (3 dispatches) =================
// prep_fast: [0,5000) h->bf16 | [5000,5256) W transpose via LDS tile |
// [5256,5335) zero cnt (replaces the hipMemsetAsync dispatch).
__global__ void prep_fast_kernel(const float* __restrict__ h, bf16_t* __restrict__ hB,
                                 const float* __restrict__ W, bf16_t* __restrict__ Wt,
                                 int* __restrict__ cnt) {
  int b = blockIdx.x;
  int t = threadIdx.x;
  if (b < 5000) {
    int i = (b * 256 + t) * 4;
    float4 v = *(const float4*)(h + i);
    bf16x4 o = { (bf16_t)v.x, (bf16_t)v.y, (bf16_t)v.z, (bf16_t)v.w };
    *(bf16x4*)(hB + i) = o;
  } else if (b < 5256) {
    // 64(i) x 64(o) tile transpose: W[r][i][o] f32 -> Wt[r][o][i] bf16
    __shared__ bf16_t lds[64][66];   // odd-dword row stride -> conflict-free
    int b2 = b - 5000;
    int r  = b2 >> 4;
    int i0 = ((b2 >> 2) & 3) << 6;
    int o0 = (b2 & 3) << 6;
    int tx = t & 15;
    int ty = t >> 4;
#pragma unroll
    for (int pass = 0; pass < 4; ++pass) {
      int il = ty + pass * 16;
      float4 v = *(const float4*)(W + (r << 16) + ((i0 + il) << 8) + o0 + tx * 4);
      lds[tx * 4 + 0][il] = (bf16_t)v.x;
      lds[tx * 4 + 1][il] = (bf16_t)v.y;
      lds[tx * 4 + 2][il] = (bf16_t)v.z;
      lds[tx * 4 + 3][il] = (bf16_t)v.w;
    }
    __syncthreads();
#pragma unroll
    for (int pass = 0; pass < 4; ++pass) {
      int ol = ty + pass * 16;
      bf16x4 pk = { lds[ol][tx * 4 + 0], lds[ol][tx * 4 + 1],
                    lds[ol][tx * 4 + 2], lds[ol][tx * 4 + 3] };
      *(bf16x4*)(Wt + (r << 16) + ((o0 + ol) << 8) + i0 + tx * 4) = pk;
    }
  } else {
    int idx = (b - 5256) * 256 + t;
    if (idx < N_NODES_C) cnt[idx] = 0;
  }
}

// ================= SLOW PATH (known-good 6-dispatch CSR chain) =================
__global__ void prep_kernel(const float* __restrict__ h, bf16_t* __restrict__ hB,
                            const float* __restrict__ W, bf16_t* __restrict__ Wt,
                            const int* __restrict__ dst, int* __restrict__ dcur) {
  int b = blockIdx.x;
  int t = threadIdx.x;
  if (b < 5000) {
    int i = (b * 256 + t) * 4;
    float4 v = *(const float4*)(h + i);
    bf16x4 o = { (bf16_t)v.x, (bf16_t)v.y, (bf16_t)v.z, (bf16_t)v.w };
    *(bf16x4*)(hB + i) = o;
  } else if (b < 9096) {
    int g = (b - 5000) * 256 + t;
    int i = g & 255;
    int o = (g >> 8) & 255;
    int r = g >> 16;
    Wt[(r << 16) + (o << 8) + i] = (bf16_t)W[(r << 16) + (i << 8) + o];
  } else {
    int e = (b - 9096) * 256 + t;
    if (e < N_EDGES_C) atomicAdd(&dcur[dst[e]], 1);
  }
}

__global__ void scan_dst_kernel(int* __restrict__ dcur, int* __restrict__ dstart) {
  __shared__ unsigned short cnt[20224];
  __shared__ int wsum[4];
  const int CH = 79;
  int t = threadIdx.x;
  int base = t * CH;
  int sum = 0;
  for (int i = 0; i < CH; ++i) {
    int idx = base + i;
    int c = (idx < N_NODES_C) ? dcur[idx] : 0;
    cnt[idx] = (unsigned short)c;
    sum += c;
  }
  int v = sum;
#pragma unroll
  for (int off = 1; off < 64; off <<= 1) {
    int u = __shfl_up(v, off);
    if ((t & 63) >= off) v += u;
  }
  if ((t & 63) == 63) wsum[t >> 6] = v;
  __syncthreads();
  int add = 0;
  for (int w = 0; w < (t >> 6); ++w) add += wsum[w];
  int run = v - sum + add;
  for (int i = 0; i < CH; ++i) {
    int idx = base + i;
    if (idx < N_NODES_C) {
      int c = cnt[idx];
      dstart[idx] = run;
      dcur[idx] = run;
      run += c;
    }
  }
  if (t == 0) dstart[N_NODES_C] = N_EDGES_C;
}

__global__ void bucket_dst_kernel(const int* __restrict__ dst, const int* __restrict__ src,
                                  const int* __restrict__ rel, const float* __restrict__ norm,
                                  int* __restrict__ dcur, int2* __restrict__ bkt) {
  int e = blockIdx.x * blockDim.x + threadIdx.x;
  if (e < N_EDGES_C) {
    int pos = atomicAdd(&dcur[dst[e]], 1);
    int2 pk;
    pk.x = src[e] | (rel[e] << 16);
    pk.y = __float_as_int(norm[e]);
    bkt[pos] = pk;
  }
}

// ---- Phase A (+ hidden bucket): R2 tile/frag math + counted-vmcnt pipeline.
// Frozen core (R1/R2/R4/R7 all neutral). NEW: Tb stores are NON-TEMPORAL —
// the 160 MB write stream no longer thrashes L2, so staged hB/Wt lines stay
// L2-resident for sibling blocks (lower staging latency inside the vmcnt stall).
// Infinity Cache (memory-side) still catches Tb for the aggregate.
__global__ __launch_bounds__(256) void gemm_bucket_kernel(
    const bf16_t* __restrict__ hB, const bf16_t* __restrict__ Wt,
    bf16_t* __restrict__ Tb,
    const int* __restrict__ dst, const int* __restrict__ src,
    const int* __restrict__ rel, const float* __restrict__ norm,
    int* __restrict__ cnt, int2* __restrict__ bkt) {
  int bx = blockIdx.x;
  int tid = threadIdx.x;

  if (bx >= GEMM_BLOCKS) {
    // ---- bucket branch: direct-bin scatter (cnt zeroed by prep dispatch) ----
    int e = (bx - GEMM_BLOCKS) * 256 + tid;
    if (e < N_EDGES_C) {
      int d = dst[e];
      int pos = (d << CAP_LOG2) + atomicAdd(&cnt[d], 1);
      int2 pk;
      pk.x = src[e] | (rel[e] << 16);
      pk.y = __float_as_int(norm[e]);
      bkt[pos] = pk;
    }
    return;
  }

  int sub = bx & 31;
  int m0 = (bx >> 5) << 7;
  int r  = sub >> 1;
  int n0 = (sub & 1) << 7;

  __shared__ bf16_t Asm[3 * 128 * 32];   // 24 KB (triple-buffered)
  __shared__ bf16_t Bsm[3 * 128 * 32];   // 24 KB

  int lrow = tid >> 2;
  int pch = tid & 3;
  int rA0 = lrow, rA1 = lrow + 64;
  int lc0 = pch ^ ((rA0 >> 1) & 3);
  int lc1 = pch ^ ((rA1 >> 1) & 3);
  int gr0 = m0 + rA0; if (gr0 > N_NODES_C - 1) gr0 = N_NODES_C - 1;
  int gr1 = m0 + rA1; if (gr1 > N_NODES_C - 1) gr1 = N_NODES_C - 1;
  const char* gA0 = (const char*)(hB + (size_t)gr0 * FEAT_C) + lc0 * 16;
  const char* gA1 = (const char*)(hB + (size_t)gr1 * FEAT_C) + lc1 * 16;
  const char* gB0 = (const char*)(Wt + ((size_t)r * 256 + n0 + rA0) * FEAT_C) + lc0 * 16;
  const char* gB1 = (const char*)(Wt + ((size_t)r * 256 + n0 + rA1) * FEAT_C) + lc1 * 16;

  int wave = tid >> 6;
  int lane = tid & 63;
  int lq = lane >> 4;
  int lr = lane & 15;
  int wm = (wave >> 1) * 64;
  int wn = (wave & 1) * 64;
  int pc8 = (lq ^ ((lr >> 1) & 3)) * 8;

  f32x4 acc[4][4] = {};

#define STAGE(buf, t)                                             \
  do {                                                            \
    int kb_ = (t) * 64;                                           \
    char* aB_ = (char*)Asm + (buf) * 8192 + wave * 1024;          \
    char* bB_ = (char*)Bsm + (buf) * 8192 + wave * 1024;          \
    async_load16(gA0 + kb_, aB_);                                 \
    async_load16(gA1 + kb_, aB_ + 4096);                          \
    async_load16(gB0 + kb_, bB_);                                 \
    async_load16(gB1 + kb_, bB_ + 4096);                          \
  } while (0)

  STAGE(0, 0);
  STAGE(1, 1);

#pragma unroll
  for (int kk = 0; kk < 8; ++kk) {
    if (kk < 7) asm volatile("s_waitcnt vmcnt(4)" ::: "memory");
    else        asm volatile("s_waitcnt vmcnt(0)" ::: "memory");
    __builtin_amdgcn_s_barrier();
    __builtin_amdgcn_sched_barrier(0);
    const bf16_t* Ac = Asm + (kk % 3) * 4096;
    const bf16_t* Bc = Bsm + (kk % 3) * 4096;
    bf16x8 af[4], bfr[4];
#pragma unroll
    for (int mt = 0; mt < 4; ++mt) {
      int row = wm + mt * 16 + lr;
      af[mt] = *(const bf16x8*)&Ac[row * 32 + pc8];
    }
#pragma unroll
    for (int nt2 = 0; nt2 < 4; ++nt2) {
      int row = wn + nt2 * 16 + lr;
      bfr[nt2] = *(const bf16x8*)&Bc[row * 32 + pc8];
    }
    if (kk < 6) STAGE((kk + 2) % 3, kk + 2);
#pragma unroll
    for (int mt = 0; mt < 4; ++mt)
#pragma unroll
      for (int nt2 = 0; nt2 < 4; ++nt2)
        acc[mt][nt2] = __builtin_amdgcn_mfma_f32_16x16x32_bf16(af[mt], bfr[nt2], acc[mt][nt2], 0, 0, 0);
  }
#undef STAGE

  // Epilogue: 16B/lane NON-TEMPORAL stores via parity-pair shfl_xor merge
  // (layout unchanged: permuted position p = 4*lr' + nt holds col nt*16 + lr').
#pragma unroll
  for (int mt = 0; mt < 4; ++mt) {
#pragma unroll
    for (int a = 0; a < 2; ++a) {
      int rg0 = a * 2, rg1 = rg0 + 1;
      union { bf16x4 v; long long u; } q0, q1;
      q0.v = (bf16x4){ (bf16_t)acc[mt][0][rg0], (bf16_t)acc[mt][1][rg0],
                       (bf16_t)acc[mt][2][rg0], (bf16_t)acc[mt][3][rg0] };
      q1.v = (bf16x4){ (bf16_t)acc[mt][0][rg1], (bf16_t)acc[mt][1][rg1],
                       (bf16_t)acc[mt][2][rg1], (bf16_t)acc[mt][3][rg1] };
      int odd = lr & 1;
      long long send = odd ? q0.u : q1.u;
      long long got = __shfl_xor(send, 1);
      union { bf16x8 v; long long u[2]; } w;
      w.u[0] = odd ? got : q0.u;
      w.u[1] = odd ? q1.u : got;
      int rg = rg0 + odd;
      int row = m0 + wm + mt * 16 + lq * 4 + rg;
      if (row < N_NODES_C) {
        int pos = n0 + wn + ((lr >> 1) << 3);
        __builtin_nontemporal_store(
            w.v, (bf16x8*)(Tb + (((size_t)r * N_NODES_C + row) << 8) + pos));
      }
    }
  }
}

// ---- Phase B: FULL WAVE per edge (64 lanes x 8B = 512B/instruction), 8-deep
// batching, NON-TEMPORAL gather loads (once-read lines skip L2 fill; L3 serves).
// Lane l reads permuted positions 4l..4l+3; de-permute on the out write:
// position 4l+j holds col (4l&192) + j*16 + (l&15)  [proven mapping, R1-R4].
template <int MODE>
__global__ __launch_bounds__(256) void aggregate_kernel(
    const bf16_t* __restrict__ Tb, const int* __restrict__ meta,
    const int2* __restrict__ bkt, float* __restrict__ out) {
  int tid = threadIdx.x;
  int d = blockIdx.x * 4 + (tid >> 6);
  int lane = tid & 63;
  int p0, p1;
  if (MODE == 0) { p0 = meta[d]; p1 = meta[d + 1]; }
  else           { p0 = d << CAP_LOG2; p1 = p0 + meta[d]; }
  int boff = lane << 3;   // byte offset: positions 4l..4l+3
  float a0 = 0.f, a1 = 0.f, a2 = 0.f, a3 = 0.f;
  int p = p0;
  // 8-deep: metas first, then 8 independent 512B gathers in flight per wave.
  for (; p + 8 <= p1; p += 8) {
    int2 m[8];
#pragma unroll
    for (int q = 0; q < 8; ++q) m[q] = bkt[p + q];
    bf16x4 v[8];
#pragma unroll
    for (int q = 0; q < 8; ++q)
      v[q] = __builtin_nontemporal_load(
          (const bf16x4*)((const char*)(Tb + (((size_t)(m[q].x >> 16) * N_NODES_C + (m[q].x & 0xFFFF)) << 8)) + boff));
#pragma unroll
    for (int q = 0; q < 8; ++q) {
      float nq = __int_as_float(m[q].y);
      a0 += (float)v[q][0] * nq;
      a1 += (float)v[q][1] * nq;
      a2 += (float)v[q][2] * nq;
      a3 += (float)v[q][3] * nq;
    }
  }
  // 4-deep tail
  if (p + 4 <= p1) {
    int2 m[4];
#pragma unroll
    for (int q = 0; q < 4; ++q) m[q] = bkt[p + q];
    bf16x4 v[4];
#pragma unroll
    for (int q = 0; q < 4; ++q)
      v[q] = __builtin_nontemporal_load(
          (const bf16x4*)((const char*)(Tb + (((size_t)(m[q].x >> 16) * N_NODES_C + (m[q].x & 0xFFFF)) << 8)) + boff));
#pragma unroll
    for (int q = 0; q < 4; ++q) {
      float nq = __int_as_float(m[q].y);
      a0 += (float)v[q][0] * nq;
      a1 += (float)v[q][1] * nq;
      a2 += (float)v[q][2] * nq;
      a3 += (float)v[q][3] * nq;
    }
    p += 4;
  }
  // scalar tail (<=3)
  for (; p < p1; ++p) {
    int2 m0 = bkt[p];
    bf16x4 v0 = __builtin_nontemporal_load(
        (const bf16x4*)((const char*)(Tb + (((size_t)(m0.x >> 16) * N_NODES_C + (m0.x & 0xFFFF)) << 8)) + boff));
    float n0 = __int_as_float(m0.y);
    a0 += (float)v0[0] * n0;
    a1 += (float)v0[1] * n0;
    a2 += (float)v0[2] * n0;
    a3 += (float)v0[3] * n0;
  }
  // De-permute write: position 4l+j -> col (4l&192) + j*16 + (l&15)
  float* o = out + (size_t)d * FEAT_C + ((lane << 2) & 192) + (lane & 15);
  o[0]  = a0;
  o[16] = a1;
  o[32] = a2;
  o[48] = a3;
}

extern "C" void kernel_launch(void* const* d_in, const int* in_sizes, int n_in,
                              void* d_out, int out_size, void* d_ws, size_t ws_size,
                              hipStream_t stream) {
  const float* h    = (const float*)d_in[0];
  const float* W    = (const float*)d_in[1];
  const float* norm = (const float*)d_in[2];
  const int*   src  = (const int*)d_in[3];
  const int*   dst  = (const int*)d_in[4];
  const int*   rel  = (const int*)d_in[5];
  float* out = (float*)d_out;

  char* ws = (char*)d_ws;
  bf16_t* hB   = (bf16_t*)ws;                          // 10,240,000 B
  bf16_t* Wt   = (bf16_t*)(ws + 10240000);             //  2,097,152 B
  bf16_t* Tb   = (bf16_t*)(ws + 12337152);             // 163,840,000 B -> 176,177,152

  if (ws_size >= WS_FAST_BYTES) {
    // ---- fast path: 3 dispatches ----
    int* cnt  = (int*)(ws + 176177152);                // 80,000 B
    int2* bkt = (int2*)(ws + 176257152);               // 10,240,000 B -> 186,497,152
    prep_fast_kernel<<<5335, 256, 0, stream>>>(h, hB, W, Wt, cnt);
    gemm_bucket_kernel<<<GEMM_BLOCKS + 1250, 256, 0, stream>>>(
        hB, Wt, Tb, dst, src, rel, norm, cnt, bkt);
    aggregate_kernel<1><<<5000, 256, 0, stream>>>(Tb, cnt, bkt, out);
  } else {
    // ---- slow path: known-good CSR chain ----
    int* dstart  = (int*)(ws + 176177152);             // 80,016 B
    int* dcur    = (int*)(ws + 176257168);             // 80,000 B
    int2* bkt    = (int2*)(ws + 176337168);            // 2,560,000 B -> ~178.9 MB
    hipMemsetAsync(dcur, 0, N_NODES_C * sizeof(int), stream);
    prep_kernel<<<10346, 256, 0, stream>>>(h, hB, W, Wt, dst, dcur);
    scan_dst_kernel<<<1, 256, 0, stream>>>(dcur, dstart);
    bucket_dst_kernel<<<1250, 256, 0, stream>>>(dst, src, rel, norm, dcur, bkt);
    gemm_bucket_kernel<<<GEMM_BLOCKS, 256, 0, stream>>>(
        hB, Wt, Tb, nullptr, nullptr, nullptr, nullptr, nullptr, nullptr);
    aggregate_kernel<0><<<5000, 256, 0, stream>>>(Tb, dstart, bkt, out);
  }
}

// Round 14
// 181.474 us; speedup vs baseline: 1.2209x; 1.0603x over previous
//
#include <hip/hip_runtime.h>
#include <stdint.h>

#define N_NODES_C 20000
#define N_EDGES_C 320000
#define NUM_RELS_C 16
#define FEAT_C 256
#define CAP_LOG2 6           // 64 slots per dst in direct-bucket fast path
#define GEMM_BLOCKS 5024     // 157 m-tiles * 32 (r*2 + n_half)
#define WS_FAST_BYTES 186497152ULL

typedef __bf16 bf16_t;
typedef __bf16 bf16x8 __attribute__((ext_vector_type(8)));
typedef __bf16 bf16x4 __attribute__((ext_vector_type(4)));
typedef float f32x4 __attribute__((ext_vector_type(4)));

__device__ __forceinline__ void async_load16(const void* g, void* l) {
  __builtin_amdgcn_global_load_lds(
      (__attribute__((address_space(1))) void*)const_cast<void*>(g),
      (__attribute__((address_space(3))) void*)l, 16, 0, 0);
}

// ================= FAST PATH (3 dispatches) =================
// prep_fast: [0,5000) h->bf16 | [5000,5256) W transpose via LDS tile |
// [5256,5335) zero cnt (replaces the hipMemsetAsync dispatch).
__global__ void prep_fast_kernel(const float* __restrict__ h, bf16_t* __restrict__ hB,
                                 const float* __restrict__ W, bf16_t* __restrict__ Wt,
                                 int* __restrict__ cnt) {
  int b = blockIdx.x;
  int t = threadIdx.x;
  if (b < 5000) {
    int i = (b * 256 + t) * 4;
    float4 v = *(const float4*)(h + i);
    bf16x4 o = { (bf16_t)v.x, (bf16_t)v.y, (bf16_t)v.z, (bf16_t)v.w };
    *(bf16x4*)(hB + i) = o;
  } else if (b < 5256) {
    // 64(i) x 64(o) tile transpose: W[r][i][o] f32 -> Wt[r][o][i] bf16
    __shared__ bf16_t lds[64][66];   // odd-dword row stride -> conflict-free
    int b2 = b - 5000;
    int r  = b2 >> 4;
    int i0 = ((b2 >> 2) & 3) << 6;
    int o0 = (b2 & 3) << 6;
    int tx = t & 15;
    int ty = t >> 4;
#pragma unroll
    for (int pass = 0; pass < 4; ++pass) {
      int il = ty + pass * 16;
      float4 v = *(const float4*)(W + (r << 16) + ((i0 + il) << 8) + o0 + tx * 4);
      lds[tx * 4 + 0][il] = (bf16_t)v.x;
      lds[tx * 4 + 1][il] = (bf16_t)v.y;
      lds[tx * 4 + 2][il] = (bf16_t)v.z;
      lds[tx * 4 + 3][il] = (bf16_t)v.w;
    }
    __syncthreads();
#pragma unroll
    for (int pass = 0; pass < 4; ++pass) {
      int ol = ty + pass * 16;
      bf16x4 pk = { lds[ol][tx * 4 + 0], lds[ol][tx * 4 + 1],
                    lds[ol][tx * 4 + 2], lds[ol][tx * 4 + 3] };
      *(bf16x4*)(Wt + (r << 16) + ((o0 + ol) << 8) + i0 + tx * 4) = pk;
    }
  } else {
    int idx = (b - 5256) * 256 + t;
    if (idx < N_NODES_C) cnt[idx] = 0;
  }
}

// ================= SLOW PATH (known-good 6-dispatch CSR chain) =================
__global__ void prep_kernel(const float* __restrict__ h, bf16_t* __restrict__ hB,
                            const float* __restrict__ W, bf16_t* __restrict__ Wt,
                            const int* __restrict__ dst, int* __restrict__ dcur) {
  int b = blockIdx.x;
  int t = threadIdx.x;
  if (b < 5000) {
    int i = (b * 256 + t) * 4;
    float4 v = *(const float4*)(h + i);
    bf16x4 o = { (bf16_t)v.x, (bf16_t)v.y, (bf16_t)v.z, (bf16_t)v.w };
    *(bf16x4*)(hB + i) = o;
  } else if (b < 9096) {
    int g = (b - 5000) * 256 + t;
    int i = g & 255;
    int o = (g >> 8) & 255;
    int r = g >> 16;
    Wt[(r << 16) + (o << 8) + i] = (bf16_t)W[(r << 16) + (i << 8) + o];
  } else {
    int e = (b - 9096) * 256 + t;
    if (e < N_EDGES_C) atomicAdd(&dcur[dst[e]], 1);
  }
}

__global__ void scan_dst_kernel(int* __restrict__ dcur, int* __restrict__ dstart) {
  __shared__ unsigned short cnt[20224];
  __shared__ int wsum[4];
  const int CH = 79;
  int t = threadIdx.x;
  int base = t * CH;
  int sum = 0;
  for (int i = 0; i < CH; ++i) {
    int idx = base + i;
    int c = (idx < N_NODES_C) ? dcur[idx] : 0;
    cnt[idx] = (unsigned short)c;
    sum += c;
  }
  int v = sum;
#pragma unroll
  for (int off = 1; off < 64; off <<= 1) {
    int u = __shfl_up(v, off);
    if ((t & 63) >= off) v += u;
  }
  if ((t & 63) == 63) wsum[t >> 6] = v;
  __syncthreads();
  int add = 0;
  for (int w = 0; w < (t >> 6); ++w) add += wsum[w];
  int run = v - sum + add;
  for (int i = 0; i < CH; ++i) {
    int idx = base + i;
    if (idx < N_NODES_C) {
      int c = cnt[idx];
      dstart[idx] = run;
      dcur[idx] = run;
      run += c;
    }
  }
  if (t == 0) dstart[N_NODES_C] = N_EDGES_C;
}

__global__ void bucket_dst_kernel(const int* __restrict__ dst, const int* __restrict__ src,
                                  const int* __restrict__ rel, const float* __restrict__ norm,
                                  int* __restrict__ dcur, int2* __restrict__ bkt) {
  int e = blockIdx.x * blockDim.x + threadIdx.x;
  if (e < N_EDGES_C) {
    int pos = atomicAdd(&dcur[dst[e]], 1);
    int2 pk;
    pk.x = src[e] | (rel[e] << 16);
    pk.y = __float_as_int(norm[e]);
    bkt[pos] = pk;
  }
}

// ---- Phase A (+ hidden bucket): R2 tile/frag math + counted-vmcnt pipeline.
// Frozen at ~62 µs core (R1/R2/R4/R7/R10/R13: barriers, depth, FETCH, store
// width, WRITE bytes, B-in-VGPR, NT hints all neutral or worse). Blocks
// [GEMM_BLOCKS, +1250) run the edge direct-bucket scatter in the dispatch tail.
__global__ __launch_bounds__(256) void gemm_bucket_kernel(
    const bf16_t* __restrict__ hB, const bf16_t* __restrict__ Wt,
    bf16_t* __restrict__ Tb,
    const int* __restrict__ dst, const int* __restrict__ src,
    const int* __restrict__ rel, const float* __restrict__ norm,
    int* __restrict__ cnt, int2* __restrict__ bkt) {
  int bx = blockIdx.x;
  int tid = threadIdx.x;

  if (bx >= GEMM_BLOCKS) {
    // ---- bucket branch: direct-bin scatter (cnt zeroed by prep dispatch) ----
    int e = (bx - GEMM_BLOCKS) * 256 + tid;
    if (e < N_EDGES_C) {
      int d = dst[e];
      int pos = (d << CAP_LOG2) + atomicAdd(&cnt[d], 1);
      int2 pk;
      pk.x = src[e] | (rel[e] << 16);
      pk.y = __float_as_int(norm[e]);
      bkt[pos] = pk;
    }
    return;
  }

  int sub = bx & 31;
  int m0 = (bx >> 5) << 7;
  int r  = sub >> 1;
  int n0 = (sub & 1) << 7;

  __shared__ bf16_t Asm[3 * 128 * 32];   // 24 KB (triple-buffered)
  __shared__ bf16_t Bsm[3 * 128 * 32];   // 24 KB

  int lrow = tid >> 2;
  int pch = tid & 3;
  int rA0 = lrow, rA1 = lrow + 64;
  int lc0 = pch ^ ((rA0 >> 1) & 3);
  int lc1 = pch ^ ((rA1 >> 1) & 3);
  int gr0 = m0 + rA0; if (gr0 > N_NODES_C - 1) gr0 = N_NODES_C - 1;
  int gr1 = m0 + rA1; if (gr1 > N_NODES_C - 1) gr1 = N_NODES_C - 1;
  const char* gA0 = (const char*)(hB + (size_t)gr0 * FEAT_C) + lc0 * 16;
  const char* gA1 = (const char*)(hB + (size_t)gr1 * FEAT_C) + lc1 * 16;
  const char* gB0 = (const char*)(Wt + ((size_t)r * 256 + n0 + rA0) * FEAT_C) + lc0 * 16;
  const char* gB1 = (const char*)(Wt + ((size_t)r * 256 + n0 + rA1) * FEAT_C) + lc1 * 16;

  int wave = tid >> 6;
  int lane = tid & 63;
  int lq = lane >> 4;
  int lr = lane & 15;
  int wm = (wave >> 1) * 64;
  int wn = (wave & 1) * 64;
  int pc8 = (lq ^ ((lr >> 1) & 3)) * 8;

  f32x4 acc[4][4] = {};

#define STAGE(buf, t)                                             \
  do {                                                            \
    int kb_ = (t) * 64;                                           \
    char* aB_ = (char*)Asm + (buf) * 8192 + wave * 1024;          \
    char* bB_ = (char*)Bsm + (buf) * 8192 + wave * 1024;          \
    async_load16(gA0 + kb_, aB_);                                 \
    async_load16(gA1 + kb_, aB_ + 4096);                          \
    async_load16(gB0 + kb_, bB_);                                 \
    async_load16(gB1 + kb_, bB_ + 4096);                          \
  } while (0)

  STAGE(0, 0);
  STAGE(1, 1);

#pragma unroll
  for (int kk = 0; kk < 8; ++kk) {
    if (kk < 7) asm volatile("s_waitcnt vmcnt(4)" ::: "memory");
    else        asm volatile("s_waitcnt vmcnt(0)" ::: "memory");
    __builtin_amdgcn_s_barrier();
    __builtin_amdgcn_sched_barrier(0);
    const bf16_t* Ac = Asm + (kk % 3) * 4096;
    const bf16_t* Bc = Bsm + (kk % 3) * 4096;
    bf16x8 af[4], bfr[4];
#pragma unroll
    for (int mt = 0; mt < 4; ++mt) {
      int row = wm + mt * 16 + lr;
      af[mt] = *(const bf16x8*)&Ac[row * 32 + pc8];
    }
#pragma unroll
    for (int nt2 = 0; nt2 < 4; ++nt2) {
      int row = wn + nt2 * 16 + lr;
      bfr[nt2] = *(const bf16x8*)&Bc[row * 32 + pc8];
    }
    if (kk < 6) STAGE((kk + 2) % 3, kk + 2);
#pragma unroll
    for (int mt = 0; mt < 4; ++mt)
#pragma unroll
      for (int nt2 = 0; nt2 < 4; ++nt2)
        acc[mt][nt2] = __builtin_amdgcn_mfma_f32_16x16x32_bf16(af[mt], bfr[nt2], acc[mt][nt2], 0, 0, 0);
  }
#undef STAGE

  // Epilogue: 16B/lane stores via parity-pair shfl_xor merge (layout unchanged:
  // permuted position p = 4*lr' + nt holds col nt*16 + lr' within the n0+wn group).
#pragma unroll
  for (int mt = 0; mt < 4; ++mt) {
#pragma unroll
    for (int a = 0; a < 2; ++a) {
      int rg0 = a * 2, rg1 = rg0 + 1;
      union { bf16x4 v; long long u; } q0, q1;
      q0.v = (bf16x4){ (bf16_t)acc[mt][0][rg0], (bf16_t)acc[mt][1][rg0],
                       (bf16_t)acc[mt][2][rg0], (bf16_t)acc[mt][3][rg0] };
      q1.v = (bf16x4){ (bf16_t)acc[mt][0][rg1], (bf16_t)acc[mt][1][rg1],
                       (bf16_t)acc[mt][2][rg1], (bf16_t)acc[mt][3][rg1] };
      int odd = lr & 1;
      long long send = odd ? q0.u : q1.u;
      long long got = __shfl_xor(send, 1);
      union { bf16x8 v; long long u[2]; } w;
      w.u[0] = odd ? got : q0.u;
      w.u[1] = odd ? q1.u : got;
      int rg = rg0 + odd;
      int row = m0 + wm + mt * 16 + lq * 4 + rg;
      if (row < N_NODES_C) {
        int pos = n0 + wn + ((lr >> 1) << 3);
        *(bf16x8*)(Tb + (((size_t)r * N_NODES_C + row) << 8) + pos) = w.v;
      }
    }
  }
}

// ---- Phase B: FULL WAVE per edge (64 lanes x 8B = 512B/instruction), 8-deep
// batching. Lane l reads permuted positions 4l..4l+3; de-permute on the out
// write: position 4l+j holds col (4l&192) + j*16 + (l&15)  [proven, R1-R4].
template <int MODE>
__global__ __launch_bounds__(256) void aggregate_kernel(
    const bf16_t* __restrict__ Tb, const int* __restrict__ meta,
    const int2* __restrict__ bkt, float* __restrict__ out) {
  int tid = threadIdx.x;
  int d = blockIdx.x * 4 + (tid >> 6);
  int lane = tid & 63;
  int p0, p1;
  if (MODE == 0) { p0 = meta[d]; p1 = meta[d + 1]; }
  else           { p0 = d << CAP_LOG2; p1 = p0 + meta[d]; }
  int boff = lane << 3;   // byte offset: positions 4l..4l+3
  float a0 = 0.f, a1 = 0.f, a2 = 0.f, a3 = 0.f;
  int p = p0;
  // 8-deep: metas first, then 8 independent 512B gathers in flight per wave.
  for (; p + 8 <= p1; p += 8) {
    int2 m[8];
#pragma unroll
    for (int q = 0; q < 8; ++q) m[q] = bkt[p + q];
    bf16x4 v[8];
#pragma unroll
    for (int q = 0; q < 8; ++q)
      v[q] = *(const bf16x4*)((const char*)(Tb + (((size_t)(m[q].x >> 16) * N_NODES_C + (m[q].x & 0xFFFF)) << 8)) + boff);
#pragma unroll
    for (int q = 0; q < 8; ++q) {
      float nq = __int_as_float(m[q].y);
      a0 += (float)v[q][0] * nq;
      a1 += (float)v[q][1] * nq;
      a2 += (float)v[q][2] * nq;
      a3 += (float)v[q][3] * nq;
    }
  }
  // 4-deep tail
  if (p + 4 <= p1) {
    int2 m[4];
#pragma unroll
    for (int q = 0; q < 4; ++q) m[q] = bkt[p + q];
    bf16x4 v[4];
#pragma unroll
    for (int q = 0; q < 4; ++q)
      v[q] = *(const bf16x4*)((const char*)(Tb + (((size_t)(m[q].x >> 16) * N_NODES_C + (m[q].x & 0xFFFF)) << 8)) + boff);
#pragma unroll
    for (int q = 0; q < 4; ++q) {
      float nq = __int_as_float(m[q].y);
      a0 += (float)v[q][0] * nq;
      a1 += (float)v[q][1] * nq;
      a2 += (float)v[q][2] * nq;
      a3 += (float)v[q][3] * nq;
    }
    p += 4;
  }
  // scalar tail (<=3)
  for (; p < p1; ++p) {
    int2 m0 = bkt[p];
    bf16x4 v0 = *(const bf16x4*)((const char*)(Tb + (((size_t)(m0.x >> 16) * N_NODES_C + (m0.x & 0xFFFF)) << 8)) + boff);
    float n0 = __int_as_float(m0.y);
    a0 += (float)v0[0] * n0;
    a1 += (float)v0[1] * n0;
    a2 += (float)v0[2] * n0;
    a3 += (float)v0[3] * n0;
  }
  // De-permute write: position 4l+j -> col (4l&192) + j*16 + (l&15)
  float* o = out + (size_t)d * FEAT_C + ((lane << 2) & 192) + (lane & 15);
  o[0]  = a0;
  o[16] = a1;
  o[32] = a2;
  o[48] = a3;
}

extern "C" void kernel_launch(void* const* d_in, const int* in_sizes, int n_in,
                              void* d_out, int out_size, void* d_ws, size_t ws_size,
                              hipStream_t stream) {
  const float* h    = (const float*)d_in[0];
  const float* W    = (const float*)d_in[1];
  const float* norm = (const float*)d_in[2];
  const int*   src  = (const int*)d_in[3];
  const int*   dst  = (const int*)d_in[4];
  const int*   rel  = (const int*)d_in[5];
  float* out = (float*)d_out;

  char* ws = (char*)d_ws;
  bf16_t* hB   = (bf16_t*)ws;                          // 10,240,000 B
  bf16_t* Wt   = (bf16_t*)(ws + 10240000);             //  2,097,152 B
  bf16_t* Tb   = (bf16_t*)(ws + 12337152);             // 163,840,000 B -> 176,177,152

  if (ws_size >= WS_FAST_BYTES) {
    // ---- fast path: 3 dispatches ----
    int* cnt  = (int*)(ws + 176177152);                // 80,000 B
    int2* bkt = (int2*)(ws + 176257152);               // 10,240,000 B -> 186,497,152
    prep_fast_kernel<<<5335, 256, 0, stream>>>(h, hB, W, Wt, cnt);
    gemm_bucket_kernel<<<GEMM_BLOCKS + 1250, 256, 0, stream>>>(
        hB, Wt, Tb, dst, src, rel, norm, cnt, bkt);
    aggregate_kernel<1><<<5000, 256, 0, stream>>>(Tb, cnt, bkt, out);
  } else {
    // ---- slow path: known-good CSR chain ----
    int* dstart  = (int*)(ws + 176177152);             // 80,016 B
    int* dcur    = (int*)(ws + 176257168);             // 80,000 B
    int2* bkt    = (int2*)(ws + 176337168);            // 2,560,000 B -> ~178.9 MB
    hipMemsetAsync(dcur, 0, N_NODES_C * sizeof(int), stream);
    prep_kernel<<<10346, 256, 0, stream>>>(h, hB, W, Wt, dst, dcur);
    scan_dst_kernel<<<1, 256, 0, stream>>>(dcur, dstart);
    bucket_dst_kernel<<<1250, 256, 0, stream>>>(dst, src, rel, norm, dcur, bkt);
    gemm_bucket_kernel<<<GEMM_BLOCKS, 256, 0, stream>>>(
        hB, Wt, Tb, nullptr, nullptr, nullptr, nullptr, nullptr, nullptr);
    aggregate_kernel<0><<<5000, 256, 0, stream>>>(Tb, dstart, bkt, out);
  }
}